// Round 2
// baseline (465.359 us; speedup 1.0000x reference)
//
#include <hip/hip_runtime.h>
#include <stdint.h>
#include <stddef.h>

// ---------------------------------------------------------------------------
// HHGNN: x = LN(route_by_type(embeds @ W[t] + b[t], mask)) ;
//        lat = adj^T @ x ; ret = adj @ lat
// Shapes: B=8, N=4096, M=2048, H=128, T=13. adj fp32 [B][N][M].
// R2 changes vs R1 (passed, 238.6us):
//  - k2/k3: depth-2 register prefetch (loads for step s+2 in flight while
//    LDS-writing s+1 and computing s; one barrier/iter) -> ~2x in-flight bytes
//  - k2 streams a bf16 copy of adj (adjbf, [n][m]) to ws; k3 reads it
//    (134MB bf16, L3-resident) instead of re-reading 268MB fp32
//  - adj fp32 loads nontemporal (read-once; keep L3 for adjbf)
//  - XCD-aligned remap b = bid&7: each XCD owns one batch -> xT/latT L2-hot
// ws: xT 8.39MB + latT 4.19MB + adjbf 134.2MB = 146.8MB (ws is ~1GB per the
// observed 1.07GB poison fills)
// ---------------------------------------------------------------------------

typedef float    f32x4_t  __attribute__((ext_vector_type(4)));
typedef __bf16   bf16x8_t __attribute__((ext_vector_type(8)));
typedef unsigned int u32x4_t __attribute__((ext_vector_type(4)));
typedef unsigned short u16x4_t __attribute__((ext_vector_type(4)));

__device__ __forceinline__ unsigned short f2bf(float f) {
    union { float f; unsigned int u; } v; v.f = f;
    unsigned int u = v.u;
    return (unsigned short)((u + 0x7FFFu + ((u >> 16) & 1u)) >> 16);
}

__device__ __forceinline__ bool mask_on(const unsigned char* m, int gid) {
    return (m[gid] | m[(gid >> 2) << 2]) != 0;
}

// ---------------------------------------------------------------------------
// Kernel 1: per-type linear + bias + mask + LayerNorm, store xT bf16 [B][H][N]
// (unchanged from R1 — est. 10-20us, revisit after GEMMs are BW-bound)
// ---------------------------------------------------------------------------
__global__ __launch_bounds__(256) void k1_typed_ln(
    const float* __restrict__ embeds,
    const int*   __restrict__ ntype,
    const unsigned char* __restrict__ mask8,
    const float* __restrict__ W,
    const float* __restrict__ bias,
    const float* __restrict__ gamma,
    const float* __restrict__ beta,
    unsigned short* __restrict__ xT)
{
    __shared__ float e_lds[128][132];
    __shared__ float W_lds[128][128];
    __shared__ float b_lds[13 * 128];
    __shared__ float g_lds[128];
    __shared__ float be_lds[128];
    __shared__ unsigned short lists[13][128];
    __shared__ int cnt[13];

    const int t   = threadIdx.x;
    const int blk = blockIdx.x;
    const int b   = blk >> 5;
    const int n0  = (blk & 31) << 7;
    const float* ebase = embeds + ((size_t)b * 4096 + n0) * 128;

    for (int it = 0; it < 16; ++it) {
        int idx = it * 256 + t;
        int n = idx >> 5, c = idx & 31;
        float4 v = *(const float4*)(ebase + n * 128 + c * 4);
        *(float4*)(&e_lds[n][c * 4]) = v;
    }
    for (int i = t; i < 13 * 128; i += 256) b_lds[i] = bias[i];
    if (t < 128) { g_lds[t] = gamma[t]; be_lds[t] = beta[t]; }
    if (t < 13) cnt[t] = 0;
    __syncthreads();

    if (t < 128) {
        int ty = ntype[(size_t)b * 4096 + n0 + t];
        int slot = atomicAdd(&cnt[ty], 1);
        lists[ty][slot] = (unsigned short)t;
    }
    __syncthreads();

    const int lane = t & 63;
    const int wv   = t >> 6;

    for (int ty = 0; ty < 13; ++ty) {
        const int c = cnt[ty];
        __syncthreads();
        if (c > 0) {
            const float* Wt = W + (size_t)ty * 128 * 128;
            for (int it = 0; it < 16; ++it) {
                int idx = it * 256 + t;
                *(float4*)(&W_lds[idx >> 5][(idx & 31) * 4]) = *(const float4*)(Wt + idx * 4);
            }
        }
        __syncthreads();
        if (c == 0) continue;

        const int ngr = (c + 3) >> 2;
        for (int g = wv; g < ngr; g += 4) {
            int base = g * 4;
            int i1 = min(base + 1, c - 1), i2 = min(base + 2, c - 1), i3 = min(base + 3, c - 1);
            int nA = lists[ty][base], nB = lists[ty][i1], nC = lists[ty][i2], nD = lists[ty][i3];
            float a0 = 0, a1 = 0, a2 = 0, a3 = 0, a4 = 0, a5 = 0, a6 = 0, a7 = 0;
            for (int h = 0; h < 128; h += 4) {
                float4 eA = *(const float4*)(&e_lds[nA][h]);
                float4 eB = *(const float4*)(&e_lds[nB][h]);
                float4 eC = *(const float4*)(&e_lds[nC][h]);
                float4 eD = *(const float4*)(&e_lds[nD][h]);
                float w0 = W_lds[h + 0][lane],      w1 = W_lds[h + 1][lane];
                float w2 = W_lds[h + 2][lane],      w3 = W_lds[h + 3][lane];
                float v0 = W_lds[h + 0][lane + 64], v1 = W_lds[h + 1][lane + 64];
                float v2 = W_lds[h + 2][lane + 64], v3 = W_lds[h + 3][lane + 64];
                a0 += eA.x * w0 + eA.y * w1 + eA.z * w2 + eA.w * w3;
                a1 += eB.x * w0 + eB.y * w1 + eB.z * w2 + eB.w * w3;
                a2 += eC.x * w0 + eC.y * w1 + eC.z * w2 + eC.w * w3;
                a3 += eD.x * w0 + eD.y * w1 + eD.z * w2 + eD.w * w3;
                a4 += eA.x * v0 + eA.y * v1 + eA.z * v2 + eA.w * v3;
                a5 += eB.x * v0 + eB.y * v1 + eB.z * v2 + eB.w * v3;
                a6 += eC.x * v0 + eC.y * v1 + eC.z * v2 + eC.w * v3;
                a7 += eD.x * v0 + eD.y * v1 + eD.z * v2 + eD.w * v3;
            }
            float bl = b_lds[ty * 128 + lane], bh = b_lds[ty * 128 + lane + 64];
            a0 += bl; a1 += bl; a2 += bl; a3 += bl;
            a4 += bh; a5 += bh; a6 += bh; a7 += bh;
            int gbase = b * 4096 + n0;
            if (mask_on(mask8, gbase + nA)) { e_lds[nA][lane] = a0; e_lds[nA][lane + 64] = a4; }
            if (mask_on(mask8, gbase + nB)) { e_lds[nB][lane] = a1; e_lds[nB][lane + 64] = a5; }
            if (mask_on(mask8, gbase + nC)) { e_lds[nC][lane] = a2; e_lds[nC][lane + 64] = a6; }
            if (mask_on(mask8, gbase + nD)) { e_lds[nD][lane] = a3; e_lds[nD][lane + 64] = a7; }
        }
    }
    __syncthreads();

    for (int i = 0; i < 32; ++i) {
        int n = wv + i * 4;
        float2 v = *(const float2*)(&e_lds[n][lane * 2]);
        float s = v.x + v.y;
        float q = v.x * v.x + v.y * v.y;
        #pragma unroll
        for (int mskw = 32; mskw >= 1; mskw >>= 1) {
            s += __shfl_xor(s, mskw);
            q += __shfl_xor(q, mskw);
        }
        float mu  = s * 0.0078125f;
        float var = q * 0.0078125f - mu * mu;
        float r   = rsqrtf(var + 1e-5f);
        float2 o;
        o.x = (v.x - mu) * r * g_lds[lane * 2]     + be_lds[lane * 2];
        o.y = (v.y - mu) * r * g_lds[lane * 2 + 1] + be_lds[lane * 2 + 1];
        *(float2*)(&e_lds[n][lane * 2]) = o;
    }
    __syncthreads();

    const int nl = t & 127;
    const int hg = t >> 7;
    unsigned short* xrow = xT + (size_t)b * 128 * 4096 + n0 + nl;
    for (int i = 0; i < 64; ++i) {
        int h = hg * 64 + i;
        xrow[(size_t)h * 4096] = f2bf(e_lds[nl][h]);
    }
}

// swizzled LDS byte offset (rows padded to 80B = 40 bf16, 4x16B data blocks)
__device__ __forceinline__ int swz(int row, int blk16) {
    return row * 80 + (((blk16 ^ ((row >> 3) & 3)) & 3) << 4);
}

// ---------------------------------------------------------------------------
// Kernel 2: latT[b][h][m] = sum_n adj[b][n][m] * x[b][n][h]
// + streams adjbf (bf16 [n][m] copy of adj) for k3.
// grid 512, b = bid&7 (XCD-aligned). 4 waves (2m x 2h), BK=32,
// depth-2 register prefetch + LDS double buffer, 1 barrier/step.
// ---------------------------------------------------------------------------
__global__ __launch_bounds__(256) void k2_lat(
    const float* __restrict__ adj,
    const unsigned short* __restrict__ xT,
    unsigned short* __restrict__ latT,
    unsigned short* __restrict__ adjbf)
{
    __shared__ unsigned short Al[2][32 * 40];   // [m][k] bf16, swizzled
    __shared__ unsigned short Bl[2][128 * 40];  // [h][k] bf16, swizzled

    const int t   = threadIdx.x;
    const int bid = blockIdx.x;
    const int b   = bid & 7;              // batch == XCD
    const int m0  = (bid >> 3) << 5;
    const float* adjb = adj + (size_t)b * 4096 * 2048;
    const unsigned short* xb = xT + (size_t)b * 128 * 4096;
    unsigned short* abf = adjbf + (size_t)b * 4096 * 2048;

    const int lane = t & 63, wv = t >> 6;
    const int wm = wv & 1, wh = wv >> 1;

    const int s_ml = (t & 7) << 2;      // A staging (t<128): 4 m's
    const int s_kp = t >> 3;            // A staging: k-pair 0..15
    const int s_h  = t >> 2;            // B staging: rows s_h, s_h+64
    const int s_u  = t & 3;             // B staging: 16B block in row

    const int g = lane >> 4;
    const int frm  = wm * 16 + (lane & 15);
    const int offA = swz(frm, g);
    int offB[4];
    #pragma unroll
    for (int j = 0; j < 4; ++j) {
        int col = wh * 64 + j * 16 + (lane & 15);
        offB[j] = swz(col, g);
    }

    f32x4_t arA[2], arB[2];
    u32x4_t brA[2], brB[2];

    auto LOADT = [&](int i, int k0) {
        if (t < 128) {
            const float* p = adjb + (size_t)(k0 + s_kp * 2) * 2048 + m0 + s_ml;
            arA[i] = __builtin_nontemporal_load((const f32x4_t*)p);
            arB[i] = __builtin_nontemporal_load((const f32x4_t*)(p + 2048));
        }
        const unsigned short* q = xb + (size_t)s_h * 4096 + k0 + s_u * 8;
        brA[i] = *(const u32x4_t*)(q);
        brB[i] = *(const u32x4_t*)(q + (size_t)64 * 4096);
    };
    auto WRITET = [&](int buf, int i, int k0) {
        if (t < 128) {
            unsigned short lo[4], hi[4];
            #pragma unroll
            for (int j = 0; j < 4; ++j) { lo[j] = f2bf(arA[i][j]); hi[j] = f2bf(arB[i][j]); }
            const int blkk = s_kp >> 2, wrd = s_kp & 3;
            #pragma unroll
            for (int j = 0; j < 4; ++j) {
                unsigned int pk = (unsigned int)lo[j] | ((unsigned int)hi[j] << 16);
                *(unsigned int*)((char*)(&Al[buf][0]) + swz(s_ml + j, blkk) + wrd * 4) = pk;
            }
            // stream bf16 copy for k3 (row-major [n][m], temporal: want L3 hits)
            const size_t row = (size_t)(k0 + s_kp * 2);
            u16x4_t r0 = { lo[0], lo[1], lo[2], lo[3] };
            u16x4_t r1 = { hi[0], hi[1], hi[2], hi[3] };
            *(u16x4_t*)(abf + row * 2048 + m0 + s_ml) = r0;
            *(u16x4_t*)(abf + (row + 1) * 2048 + m0 + s_ml) = r1;
        }
        *(u32x4_t*)((char*)(&Bl[buf][0]) + swz(s_h, s_u)) = brA[i];
        *(u32x4_t*)((char*)(&Bl[buf][0]) + swz(s_h + 64, s_u)) = brB[i];
    };

    f32x4_t acc[4];
    #pragma unroll
    for (int j = 0; j < 4; ++j) acc[j] = f32x4_t{0.f, 0.f, 0.f, 0.f};

    LOADT(0, 0);
    LOADT(1, 32);
    WRITET(0, 0, 0);
    __syncthreads();

    for (int s = 0; s < 128; ++s) {
        const int buf = s & 1;
        if (s + 2 < 128) LOADT(buf, (s + 2) * 32);           // set[buf] is free
        if (s + 1 < 128) WRITET(buf ^ 1, buf ^ 1, (s + 1) * 32);
        bf16x8_t af = __builtin_bit_cast(bf16x8_t,
            *(const u32x4_t*)((const char*)(&Al[buf][0]) + offA));
        #pragma unroll
        for (int j = 0; j < 4; ++j) {
            bf16x8_t bfj = __builtin_bit_cast(bf16x8_t,
                *(const u32x4_t*)((const char*)(&Bl[buf][0]) + offB[j]));
            acc[j] = __builtin_amdgcn_mfma_f32_16x16x32_bf16(af, bfj, acc[j], 0, 0, 0);
        }
        __syncthreads();
    }

    const int mrow = m0 + wm * 16 + (lane >> 4) * 4;
    #pragma unroll
    for (int j = 0; j < 4; ++j) {
        int col = wh * 64 + j * 16 + (lane & 15);
        unsigned int o0 = (unsigned int)f2bf(acc[j][0]) | ((unsigned int)f2bf(acc[j][1]) << 16);
        unsigned int o1 = (unsigned int)f2bf(acc[j][2]) | ((unsigned int)f2bf(acc[j][3]) << 16);
        unsigned int* dst = (unsigned int*)(latT + (size_t)(b * 128 + col) * 2048 + mrow);
        dst[0] = o0; dst[1] = o1;
    }
}

// ---------------------------------------------------------------------------
// Kernel 3: ret[b][n][h] = sum_m adjbf[b][n][m] * latT[b][h][m]
// A is now bf16 (written by k2, L3-resident): no conversion, half the bytes.
// grid 512, b = bid&7. depth-2 register prefetch, 1 barrier/step.
// ---------------------------------------------------------------------------
__global__ __launch_bounds__(256) void k3_ret(
    const unsigned short* __restrict__ adjbf,
    const unsigned short* __restrict__ latT,
    float* __restrict__ ret)
{
    __shared__ unsigned short Al[2][64 * 40];   // [n][k]
    __shared__ unsigned short Bl[2][128 * 40];  // [h][k]

    const int t   = threadIdx.x;
    const int bid = blockIdx.x;
    const int b   = bid & 7;
    const int n0  = (bid >> 3) << 6;
    const unsigned short* ab = adjbf + (size_t)b * 4096 * 2048;
    const unsigned short* lb = latT + (size_t)b * 128 * 2048;

    const int lane = t & 63, wv = t >> 6;
    const int wm = wv & 1, wh = wv >> 1;

    const int s_r = t >> 2;        // A row 0..63, B rows s_r, s_r+64
    const int s_u = t & 3;         // 16B block in row

    const int g = lane >> 4;
    int offA[2];
    #pragma unroll
    for (int f = 0; f < 2; ++f) {
        int row = wm * 32 + f * 16 + (lane & 15);
        offA[f] = swz(row, g);
    }
    int offB[4];
    #pragma unroll
    for (int j = 0; j < 4; ++j) {
        int col = wh * 64 + j * 16 + (lane & 15);
        offB[j] = swz(col, g);
    }

    u32x4_t aA[2], brA[2], brB[2];

    auto LOADT = [&](int i, int k0) {
        aA[i]  = *(const u32x4_t*)(ab + (size_t)(n0 + s_r) * 2048 + k0 + s_u * 8);
        const unsigned short* q = lb + (size_t)s_r * 2048 + k0 + s_u * 8;
        brA[i] = *(const u32x4_t*)(q);
        brB[i] = *(const u32x4_t*)(q + (size_t)64 * 2048);
    };
    auto WRITET = [&](int buf, int i) {
        *(u32x4_t*)((char*)(&Al[buf][0]) + swz(s_r, s_u)) = aA[i];
        *(u32x4_t*)((char*)(&Bl[buf][0]) + swz(s_r, s_u)) = brA[i];
        *(u32x4_t*)((char*)(&Bl[buf][0]) + swz(s_r + 64, s_u)) = brB[i];
    };

    f32x4_t acc[2][4];
    #pragma unroll
    for (int f = 0; f < 2; ++f)
        #pragma unroll
        for (int j = 0; j < 4; ++j) acc[f][j] = f32x4_t{0.f, 0.f, 0.f, 0.f};

    LOADT(0, 0);
    LOADT(1, 32);
    WRITET(0, 0);
    __syncthreads();

    for (int s = 0; s < 64; ++s) {
        const int buf = s & 1;
        if (s + 2 < 64) LOADT(buf, (s + 2) * 32);
        if (s + 1 < 64) WRITET(buf ^ 1, buf ^ 1);
        bf16x8_t af0 = __builtin_bit_cast(bf16x8_t,
            *(const u32x4_t*)((const char*)(&Al[buf][0]) + offA[0]));
        bf16x8_t af1 = __builtin_bit_cast(bf16x8_t,
            *(const u32x4_t*)((const char*)(&Al[buf][0]) + offA[1]));
        #pragma unroll
        for (int j = 0; j < 4; ++j) {
            bf16x8_t bfj = __builtin_bit_cast(bf16x8_t,
                *(const u32x4_t*)((const char*)(&Bl[buf][0]) + offB[j]));
            acc[0][j] = __builtin_amdgcn_mfma_f32_16x16x32_bf16(af0, bfj, acc[0][j], 0, 0, 0);
            acc[1][j] = __builtin_amdgcn_mfma_f32_16x16x32_bf16(af1, bfj, acc[1][j], 0, 0, 0);
        }
        __syncthreads();
    }

    #pragma unroll
    for (int f = 0; f < 2; ++f) {
        int nrow = n0 + wm * 32 + f * 16 + (lane >> 4) * 4;
        #pragma unroll
        for (int j = 0; j < 4; ++j) {
            int col = wh * 64 + j * 16 + (lane & 15);
            #pragma unroll
            for (int jj = 0; jj < 4; ++jj) {
                __builtin_nontemporal_store(acc[f][j][jj],
                    &ret[((size_t)b * 4096 + nrow + jj) * 128 + col]);
            }
        }
    }
}

// ---------------------------------------------------------------------------
extern "C" void kernel_launch(void* const* d_in, const int* in_sizes, int n_in,
                              void* d_out, int out_size, void* d_ws, size_t ws_size,
                              hipStream_t stream) {
    const float* adj    = (const float*)d_in[0];
    const float* embeds = (const float*)d_in[1];
    const int*   ntype  = (const int*)d_in[2];
    const unsigned char* mask8 = (const unsigned char*)d_in[3];
    const float* W      = (const float*)d_in[4];
    const float* bias   = (const float*)d_in[5];
    const float* gamma  = (const float*)d_in[6];
    const float* beta   = (const float*)d_in[7];
    float* ret = (float*)d_out;

    unsigned short* xT    = (unsigned short*)d_ws;                  // 8*128*4096
    unsigned short* latT  = xT + (size_t)8 * 128 * 4096;            // 8*128*2048
    unsigned short* adjbf = latT + (size_t)8 * 128 * 2048;          // 8*4096*2048
    // ws needed: 146,800,640 bytes (poison fills show ws ~1GB)

    hipLaunchKernelGGL(k1_typed_ln, dim3(256), dim3(256), 0, stream,
                       embeds, ntype, mask8, W, bias, gamma, beta, xT);
    hipLaunchKernelGGL(k2_lat, dim3(512), dim3(256), 0, stream, adj, xT, latT, adjbf);
    hipLaunchKernelGGL(k3_ret, dim3(512), dim3(256), 0, stream, adjbf, latT, ret);
}

// Round 3
// 289.715 us; speedup vs baseline: 1.6063x; 1.6063x over previous
//
#include <hip/hip_runtime.h>
#include <stdint.h>
#include <stddef.h>

// ---------------------------------------------------------------------------
// HHGNN: x = LN(route_by_type(embeds @ W[t] + b[t], mask)) ;
//        lat = adj^T @ x ; ret = adj @ lat
// Shapes: B=8, N=4096, M=2048, H=128, T=13. adj fp32 [B][N][M].
// R3 vs R2 (465us, failed theory): revert ALL R2 deltas (adjbf, nt loads,
// depth-2 regs). One lever: split-K for both GEMMs.
//  k2: grid 2048 (8b x 64mt x 4nc), 32 steps each, fp32 partials -> k2_red
//  k3: grid 2048 (8b x 64nt x 4kc), 16 steps each, fp32 partials -> k3_red
// Rationale: R2 counters showed k2 at 952 GB/s, 21% occupancy, 2 blocks/CU in
// barrier lockstep -> latency-bound. 4x blocks => 6+ blocks/CU interleaved.
// ws: xT 8.39M + latT 4.19M + pLat 33.55M + pRet 67.1M = 113.2MB
// ---------------------------------------------------------------------------

typedef float    f32x4_t  __attribute__((ext_vector_type(4)));
typedef __bf16   bf16x8_t __attribute__((ext_vector_type(8)));
typedef unsigned int u32x4_t __attribute__((ext_vector_type(4)));
typedef unsigned short u16x4_t __attribute__((ext_vector_type(4)));

__device__ __forceinline__ unsigned short f2bf(float f) {
    union { float f; unsigned int u; } v; v.f = f;
    unsigned int u = v.u;
    return (unsigned short)((u + 0x7FFFu + ((u >> 16) & 1u)) >> 16);
}

__device__ __forceinline__ bool mask_on(const unsigned char* m, int gid) {
    return (m[gid] | m[(gid >> 2) << 2]) != 0;
}

// ---------------------------------------------------------------------------
// Kernel 1: per-type linear + bias + mask + LayerNorm -> xT bf16 [B][H][N]
// (unchanged from R1)
// ---------------------------------------------------------------------------
__global__ __launch_bounds__(256) void k1_typed_ln(
    const float* __restrict__ embeds,
    const int*   __restrict__ ntype,
    const unsigned char* __restrict__ mask8,
    const float* __restrict__ W,
    const float* __restrict__ bias,
    const float* __restrict__ gamma,
    const float* __restrict__ beta,
    unsigned short* __restrict__ xT)
{
    __shared__ float e_lds[128][132];
    __shared__ float W_lds[128][128];
    __shared__ float b_lds[13 * 128];
    __shared__ float g_lds[128];
    __shared__ float be_lds[128];
    __shared__ unsigned short lists[13][128];
    __shared__ int cnt[13];

    const int t   = threadIdx.x;
    const int blk = blockIdx.x;
    const int b   = blk >> 5;
    const int n0  = (blk & 31) << 7;
    const float* ebase = embeds + ((size_t)b * 4096 + n0) * 128;

    for (int it = 0; it < 16; ++it) {
        int idx = it * 256 + t;
        int n = idx >> 5, c = idx & 31;
        float4 v = *(const float4*)(ebase + n * 128 + c * 4);
        *(float4*)(&e_lds[n][c * 4]) = v;
    }
    for (int i = t; i < 13 * 128; i += 256) b_lds[i] = bias[i];
    if (t < 128) { g_lds[t] = gamma[t]; be_lds[t] = beta[t]; }
    if (t < 13) cnt[t] = 0;
    __syncthreads();

    if (t < 128) {
        int ty = ntype[(size_t)b * 4096 + n0 + t];
        int slot = atomicAdd(&cnt[ty], 1);
        lists[ty][slot] = (unsigned short)t;
    }
    __syncthreads();

    const int lane = t & 63;
    const int wv   = t >> 6;

    for (int ty = 0; ty < 13; ++ty) {
        const int c = cnt[ty];
        __syncthreads();
        if (c > 0) {
            const float* Wt = W + (size_t)ty * 128 * 128;
            for (int it = 0; it < 16; ++it) {
                int idx = it * 256 + t;
                *(float4*)(&W_lds[idx >> 5][(idx & 31) * 4]) = *(const float4*)(Wt + idx * 4);
            }
        }
        __syncthreads();
        if (c == 0) continue;

        const int ngr = (c + 3) >> 2;
        for (int g = wv; g < ngr; g += 4) {
            int base = g * 4;
            int i1 = min(base + 1, c - 1), i2 = min(base + 2, c - 1), i3 = min(base + 3, c - 1);
            int nA = lists[ty][base], nB = lists[ty][i1], nC = lists[ty][i2], nD = lists[ty][i3];
            float a0 = 0, a1 = 0, a2 = 0, a3 = 0, a4 = 0, a5 = 0, a6 = 0, a7 = 0;
            for (int h = 0; h < 128; h += 4) {
                float4 eA = *(const float4*)(&e_lds[nA][h]);
                float4 eB = *(const float4*)(&e_lds[nB][h]);
                float4 eC = *(const float4*)(&e_lds[nC][h]);
                float4 eD = *(const float4*)(&e_lds[nD][h]);
                float w0 = W_lds[h + 0][lane],      w1 = W_lds[h + 1][lane];
                float w2 = W_lds[h + 2][lane],      w3 = W_lds[h + 3][lane];
                float v0 = W_lds[h + 0][lane + 64], v1 = W_lds[h + 1][lane + 64];
                float v2 = W_lds[h + 2][lane + 64], v3 = W_lds[h + 3][lane + 64];
                a0 += eA.x * w0 + eA.y * w1 + eA.z * w2 + eA.w * w3;
                a1 += eB.x * w0 + eB.y * w1 + eB.z * w2 + eB.w * w3;
                a2 += eC.x * w0 + eC.y * w1 + eC.z * w2 + eC.w * w3;
                a3 += eD.x * w0 + eD.y * w1 + eD.z * w2 + eD.w * w3;
                a4 += eA.x * v0 + eA.y * v1 + eA.z * v2 + eA.w * v3;
                a5 += eB.x * v0 + eB.y * v1 + eB.z * v2 + eB.w * v3;
                a6 += eC.x * v0 + eC.y * v1 + eC.z * v2 + eC.w * v3;
                a7 += eD.x * v0 + eD.y * v1 + eD.z * v2 + eD.w * v3;
            }
            float bl = b_lds[ty * 128 + lane], bh = b_lds[ty * 128 + lane + 64];
            a0 += bl; a1 += bl; a2 += bl; a3 += bl;
            a4 += bh; a5 += bh; a6 += bh; a7 += bh;
            int gbase = b * 4096 + n0;
            if (mask_on(mask8, gbase + nA)) { e_lds[nA][lane] = a0; e_lds[nA][lane + 64] = a4; }
            if (mask_on(mask8, gbase + nB)) { e_lds[nB][lane] = a1; e_lds[nB][lane + 64] = a5; }
            if (mask_on(mask8, gbase + nC)) { e_lds[nC][lane] = a2; e_lds[nC][lane + 64] = a6; }
            if (mask_on(mask8, gbase + nD)) { e_lds[nD][lane] = a3; e_lds[nD][lane + 64] = a7; }
        }
    }
    __syncthreads();

    for (int i = 0; i < 32; ++i) {
        int n = wv + i * 4;
        float2 v = *(const float2*)(&e_lds[n][lane * 2]);
        float s = v.x + v.y;
        float q = v.x * v.x + v.y * v.y;
        #pragma unroll
        for (int mskw = 32; mskw >= 1; mskw >>= 1) {
            s += __shfl_xor(s, mskw);
            q += __shfl_xor(q, mskw);
        }
        float mu  = s * 0.0078125f;
        float var = q * 0.0078125f - mu * mu;
        float r   = rsqrtf(var + 1e-5f);
        float2 o;
        o.x = (v.x - mu) * r * g_lds[lane * 2]     + be_lds[lane * 2];
        o.y = (v.y - mu) * r * g_lds[lane * 2 + 1] + be_lds[lane * 2 + 1];
        *(float2*)(&e_lds[n][lane * 2]) = o;
    }
    __syncthreads();

    const int nl = t & 127;
    const int hg = t >> 7;
    unsigned short* xrow = xT + (size_t)b * 128 * 4096 + n0 + nl;
    for (int i = 0; i < 64; ++i) {
        int h = hg * 64 + i;
        xrow[(size_t)h * 4096] = f2bf(e_lds[nl][h]);
    }
}

// swizzled LDS byte offset (rows padded to 80B = 40 bf16, 4x16B data blocks)
__device__ __forceinline__ int swz(int row, int blk16) {
    return row * 80 + (((blk16 ^ ((row >> 3) & 3)) & 3) << 4);
}

// ---------------------------------------------------------------------------
// Kernel 2: pLat[b][nc][h][m] = sum_{n in chunk nc} adj[b][n][m] * x[b][n][h]
// grid 2048 = 8b x 64mt x 4nc. 4 waves (2m x 2h), BK=32, 32 steps.
// Inner loop identical to R1 (single reg set, 1 barrier/step).
// ---------------------------------------------------------------------------
__global__ __launch_bounds__(256) void k2_lat(
    const float* __restrict__ adj,
    const unsigned short* __restrict__ xT,
    float* __restrict__ pLat)
{
    __shared__ unsigned short Al[2][32 * 40];   // [m][k] bf16, swizzled
    __shared__ unsigned short Bl[2][128 * 40];  // [h][k] bf16, swizzled

    const int t   = threadIdx.x;
    const int bid = blockIdx.x;
    const int b   = bid & 7;              // batch == XCD round-robin
    const int r   = bid >> 3;             // 0..255
    const int m0  = (r & 63) << 5;
    const int nbase = (r >> 6) << 10;     // nc * 1024
    const int nc  = r >> 6;
    const float* adjb = adj + (size_t)b * 4096 * 2048;
    const unsigned short* xb = xT + (size_t)b * 128 * 4096;

    const int lane = t & 63, wv = t >> 6;
    const int wm = wv & 1, wh = wv >> 1;

    const int s_ml = (t & 7) << 2;      // A staging (t<128): 4 m's
    const int s_kp = t >> 3;            // A staging: k-pair 0..15
    const int s_h  = t >> 2;            // B staging: rows s_h, s_h+64
    const int s_u  = t & 3;             // B staging: 16B block in row

    const int g = lane >> 4;
    const int frm  = wm * 16 + (lane & 15);
    const int offA = swz(frm, g);
    int offB[4];
    #pragma unroll
    for (int j = 0; j < 4; ++j) {
        int col = wh * 64 + j * 16 + (lane & 15);
        offB[j] = swz(col, g);
    }

    float4 ar0, ar1;
    u32x4_t br0, br1;

    auto LOADT = [&](int k0) {
        if (t < 128) {
            const float* p = adjb + (size_t)(nbase + k0 + s_kp * 2) * 2048 + m0 + s_ml;
            ar0 = *(const float4*)(p);
            ar1 = *(const float4*)(p + 2048);
        }
        const unsigned short* q = xb + (size_t)s_h * 4096 + nbase + k0 + s_u * 8;
        br0 = *(const u32x4_t*)(q);
        br1 = *(const u32x4_t*)(q + (size_t)64 * 4096);
    };
    auto WRITET = [&](int buf) {
        if (t < 128) {
            const int blkk = s_kp >> 2, wrd = s_kp & 3;
            float lo[4] = {ar0.x, ar0.y, ar0.z, ar0.w};
            float hi[4] = {ar1.x, ar1.y, ar1.z, ar1.w};
            #pragma unroll
            for (int j = 0; j < 4; ++j) {
                unsigned int pk = (unsigned int)f2bf(lo[j]) | ((unsigned int)f2bf(hi[j]) << 16);
                *(unsigned int*)((char*)(&Al[buf][0]) + swz(s_ml + j, blkk) + wrd * 4) = pk;
            }
        }
        *(u32x4_t*)((char*)(&Bl[buf][0]) + swz(s_h, s_u)) = br0;
        *(u32x4_t*)((char*)(&Bl[buf][0]) + swz(s_h + 64, s_u)) = br1;
    };

    f32x4_t acc[4];
    #pragma unroll
    for (int j = 0; j < 4; ++j) acc[j] = f32x4_t{0.f, 0.f, 0.f, 0.f};

    LOADT(0);
    WRITET(0);
    for (int s = 0; s < 32; ++s) {
        if (s < 31) LOADT((s + 1) * 32);
        __syncthreads();
        const int buf = s & 1;
        bf16x8_t af = __builtin_bit_cast(bf16x8_t,
            *(const u32x4_t*)((const char*)(&Al[buf][0]) + offA));
        #pragma unroll
        for (int j = 0; j < 4; ++j) {
            bf16x8_t bfj = __builtin_bit_cast(bf16x8_t,
                *(const u32x4_t*)((const char*)(&Bl[buf][0]) + offB[j]));
            acc[j] = __builtin_amdgcn_mfma_f32_16x16x32_bf16(af, bfj, acc[j], 0, 0, 0);
        }
        if (s < 31) WRITET(buf ^ 1);
    }

    // partial store fp32: C layout col=h=lane&15 grp, rows = m
    const int mrow = m0 + wm * 16 + (lane >> 4) * 4;
    #pragma unroll
    for (int j = 0; j < 4; ++j) {
        int col = wh * 64 + j * 16 + (lane & 15);
        float4 v = make_float4(acc[j][0], acc[j][1], acc[j][2], acc[j][3]);
        *(float4*)(pLat + ((size_t)(b * 4 + nc) * 128 + col) * 2048 + mrow) = v;
    }
}

// latT[b][h][m] = bf16( sum_nc pLat[b][nc][h][m] )
__global__ __launch_bounds__(256) void k2_red(
    const float* __restrict__ pLat,
    unsigned short* __restrict__ latT)
{
    const int tid = blockIdx.x * 256 + threadIdx.x;   // 2048 blocks -> 524288
    const int m4  = tid & 511;
    const int bh  = tid >> 9;            // b*128+h, 0..1023
    const int b   = bh >> 7;
    const size_t base = ((size_t)(b * 4) * 128 + (bh & 127)) * 2048 + m4 * 4;
    f32x4_t s = *(const f32x4_t*)(pLat + base);
    #pragma unroll
    for (int nc = 1; nc < 4; ++nc) {
        f32x4_t v = *(const f32x4_t*)(pLat + base + (size_t)nc * 128 * 2048);
        s += v;
    }
    u16x4_t o = { f2bf(s[0]), f2bf(s[1]), f2bf(s[2]), f2bf(s[3]) };
    *(u16x4_t*)(latT + (size_t)bh * 2048 + m4 * 4) = o;
}

// ---------------------------------------------------------------------------
// Kernel 3: pRet[kc][b][n][h] = sum_{m in chunk kc} adj[b][n][m] * latT[b][h][m]
// grid 2048 = 8b x 64nt x 4kc. 16 steps. Inner loop identical to R1.
// ---------------------------------------------------------------------------
__global__ __launch_bounds__(256) void k3_ret(
    const float* __restrict__ adj,
    const unsigned short* __restrict__ latT,
    float* __restrict__ pRet)
{
    __shared__ unsigned short Al[2][64 * 40];   // [n][k]
    __shared__ unsigned short Bl[2][128 * 40];  // [h][k]

    const int t   = threadIdx.x;
    const int bid = blockIdx.x;
    const int b   = bid & 7;
    const int r   = bid >> 3;
    const int n0  = (r & 63) << 6;
    const int kc  = r >> 6;
    const int kbase = kc << 9;            // kc * 512
    const float* adjb = adj + (size_t)b * 4096 * 2048;
    const unsigned short* lb = latT + (size_t)b * 128 * 2048;

    const int lane = t & 63, wv = t >> 6;
    const int wm = wv & 1, wh = wv >> 1;

    const int s_r = t >> 3;        // A rows s_r, s_r+32
    const int s_c = t & 7;         // A: float4 chunk (4 k's)
    const int s_h = t >> 2;        // B rows s_h, s_h+64
    const int s_u = t & 3;

    const int g = lane >> 4;
    int offA[2];
    #pragma unroll
    for (int f = 0; f < 2; ++f) {
        int row = wm * 32 + f * 16 + (lane & 15);
        offA[f] = swz(row, g);
    }
    int offB[4];
    #pragma unroll
    for (int j = 0; j < 4; ++j) {
        int col = wh * 64 + j * 16 + (lane & 15);
        offB[j] = swz(col, g);
    }

    float4 ar0, ar1;
    u32x4_t br0, br1;

    auto LOADT = [&](int k0) {
        const float* p = adjb + (size_t)(n0 + s_r) * 2048 + kbase + k0 + s_c * 4;
        ar0 = *(const float4*)(p);
        ar1 = *(const float4*)(p + (size_t)32 * 2048);
        const unsigned short* q = lb + (size_t)s_h * 2048 + kbase + k0 + s_u * 8;
        br0 = *(const u32x4_t*)(q);
        br1 = *(const u32x4_t*)(q + (size_t)64 * 2048);
    };
    auto WRITET = [&](int buf) {
        #pragma unroll
        for (int it = 0; it < 2; ++it) {
            int row  = s_r + it * 32;
            float4 a = it ? ar1 : ar0;
            unsigned int u0 = (unsigned int)f2bf(a.x) | ((unsigned int)f2bf(a.y) << 16);
            unsigned int u1 = (unsigned int)f2bf(a.z) | ((unsigned int)f2bf(a.w) << 16);
            unsigned int* d = (unsigned int*)((char*)(&Al[buf][0]) + swz(row, s_c >> 1) + (s_c & 1) * 8);
            d[0] = u0; d[1] = u1;
        }
        *(u32x4_t*)((char*)(&Bl[buf][0]) + swz(s_h, s_u)) = br0;
        *(u32x4_t*)((char*)(&Bl[buf][0]) + swz(s_h + 64, s_u)) = br1;
    };

    f32x4_t acc[2][4];
    #pragma unroll
    for (int f = 0; f < 2; ++f)
        #pragma unroll
        for (int j = 0; j < 4; ++j) acc[f][j] = f32x4_t{0.f, 0.f, 0.f, 0.f};

    LOADT(0);
    WRITET(0);
    for (int s = 0; s < 16; ++s) {
        if (s < 15) LOADT((s + 1) * 32);
        __syncthreads();
        const int buf = s & 1;
        bf16x8_t af0 = __builtin_bit_cast(bf16x8_t,
            *(const u32x4_t*)((const char*)(&Al[buf][0]) + offA[0]));
        bf16x8_t af1 = __builtin_bit_cast(bf16x8_t,
            *(const u32x4_t*)((const char*)(&Al[buf][0]) + offA[1]));
        #pragma unroll
        for (int j = 0; j < 4; ++j) {
            bf16x8_t bfj = __builtin_bit_cast(bf16x8_t,
                *(const u32x4_t*)((const char*)(&Bl[buf][0]) + offB[j]));
            acc[0][j] = __builtin_amdgcn_mfma_f32_16x16x32_bf16(af0, bfj, acc[0][j], 0, 0, 0);
            acc[1][j] = __builtin_amdgcn_mfma_f32_16x16x32_bf16(af1, bfj, acc[1][j], 0, 0, 0);
        }
        if (s < 15) WRITET(buf ^ 1);
    }

    #pragma unroll
    for (int f = 0; f < 2; ++f) {
        int nrow = n0 + wm * 32 + f * 16 + (lane >> 4) * 4;
        #pragma unroll
        for (int j = 0; j < 4; ++j) {
            int col = wh * 64 + j * 16 + (lane & 15);
            #pragma unroll
            for (int jj = 0; jj < 4; ++jj) {
                pRet[((size_t)(kc * 8 + b) * 4096 + nrow + jj) * 128 + col] = acc[f][j][jj];
            }
        }
    }
}

// ret[b][n][h] = sum_kc pRet[kc][b][n][h]
__global__ __launch_bounds__(256) void k3_red(
    const float* __restrict__ pRet,
    float* __restrict__ ret)
{
    const int tid = blockIdx.x * 256 + threadIdx.x;   // 4096 blocks -> 1048576
    const size_t base = (size_t)tid * 4;              // over b*n*h
    f32x4_t s = *(const f32x4_t*)(pRet + base);
    #pragma unroll
    for (int kc = 1; kc < 4; ++kc) {
        f32x4_t v = *(const f32x4_t*)(pRet + base + (size_t)kc * 8 * 4096 * 128);
        s += v;
    }
    *(f32x4_t*)(ret + base) = s;
}

// ---------------------------------------------------------------------------
extern "C" void kernel_launch(void* const* d_in, const int* in_sizes, int n_in,
                              void* d_out, int out_size, void* d_ws, size_t ws_size,
                              hipStream_t stream) {
    const float* adj    = (const float*)d_in[0];
    const float* embeds = (const float*)d_in[1];
    const int*   ntype  = (const int*)d_in[2];
    const unsigned char* mask8 = (const unsigned char*)d_in[3];
    const float* W      = (const float*)d_in[4];
    const float* bias   = (const float*)d_in[5];
    const float* gamma  = (const float*)d_in[6];
    const float* beta   = (const float*)d_in[7];
    float* ret = (float*)d_out;

    unsigned short* xT   = (unsigned short*)d_ws;                   // 8.39 MB
    unsigned short* latT = xT + (size_t)8 * 128 * 4096;             // 4.19 MB
    float* pLat = (float*)(latT + (size_t)8 * 128 * 2048);          // 33.55 MB
    float* pRet = pLat + (size_t)8 * 4 * 128 * 2048;                // 67.1 MB
    // ws needed: 113.2 MB

    hipLaunchKernelGGL(k1_typed_ln, dim3(256), dim3(256), 0, stream,
                       embeds, ntype, mask8, W, bias, gamma, beta, xT);
    hipLaunchKernelGGL(k2_lat, dim3(2048), dim3(256), 0, stream, adj, xT, pLat);
    hipLaunchKernelGGL(k2_red, dim3(2048), dim3(256), 0, stream, pLat, latT);
    hipLaunchKernelGGL(k3_ret, dim3(2048), dim3(256), 0, stream, adj, latT, pRet);
    hipLaunchKernelGGL(k3_red, dim3(4096), dim3(256), 0, stream, pRet, ret);
}

// Round 4
// 249.866 us; speedup vs baseline: 1.8624x; 1.1595x over previous
//
#include <hip/hip_runtime.h>
#include <stdint.h>
#include <stddef.h>

// ---------------------------------------------------------------------------
// HHGNN: x = LN(route_by_type(embeds @ W[t] + b[t], mask)) ;
//        lat = adj^T @ x ; ret = adj @ lat
// Shapes: B=8, N=4096, M=2048, H=128, T=13. adj fp32 [B][N][M].
// R4 vs R3 (289.7us): revert split-K (no pLat/pRet/reduces). Two levers:
//  1) barrier moved to END of step: {LOAD(s+1); COMPUTE(s); WRITE(s+1); bar}
//     -> loads in flight across the whole compute phase (R1/R3 had
//     {LOAD; bar(vmcnt0 drain!); COMPUTE; WRITE} = full HBM latency exposed
//     per step; that, not wave count, was the limiter — R3 proved 3x waves
//     bought nothing).
//  2) v_cvt_pk_bf16_f32 replaces manual f2bf bit-twiddle in GEMM staging
//     (1 VALU per 2 elems vs ~5 per elem; R2 showed VALUBusy 43% @ 21% occ).
// k2: grid 512 (8b x 64mt), 128 steps BK=32. k3: grid 1024 (8b x 128nt of
// 32 rows), 64 steps. ws: xT 8.39MB + latT 4.19MB.
// ---------------------------------------------------------------------------

typedef float    f32x4_t  __attribute__((ext_vector_type(4)));
typedef __bf16   bf16x8_t __attribute__((ext_vector_type(8)));
typedef unsigned int u32x4_t __attribute__((ext_vector_type(4)));
typedef unsigned int u32x2_t __attribute__((ext_vector_type(2)));
typedef unsigned short u16x4_t __attribute__((ext_vector_type(4)));

__device__ __forceinline__ unsigned short f2bf(float f) {
    union { float f; unsigned int u; } v; v.f = f;
    unsigned int u = v.u;
    return (unsigned short)((u + 0x7FFFu + ((u >> 16) & 1u)) >> 16);
}

// packed RNE fp32x2 -> bf16x2 (lo = a, hi = b)
__device__ __forceinline__ unsigned int cvtpk(float a, float b) {
    unsigned int r;
    asm("v_cvt_pk_bf16_f32 %0, %1, %2" : "=v"(r) : "v"(a), "v"(b));
    return r;
}

__device__ __forceinline__ bool mask_on(const unsigned char* m, int gid) {
    return (m[gid] | m[(gid >> 2) << 2]) != 0;
}

// ---------------------------------------------------------------------------
// Kernel 1: per-type linear + bias + mask + LayerNorm -> xT bf16 [B][H][N]
// (unchanged from R1)
// ---------------------------------------------------------------------------
__global__ __launch_bounds__(256) void k1_typed_ln(
    const float* __restrict__ embeds,
    const int*   __restrict__ ntype,
    const unsigned char* __restrict__ mask8,
    const float* __restrict__ W,
    const float* __restrict__ bias,
    const float* __restrict__ gamma,
    const float* __restrict__ beta,
    unsigned short* __restrict__ xT)
{
    __shared__ float e_lds[128][132];
    __shared__ float W_lds[128][128];
    __shared__ float b_lds[13 * 128];
    __shared__ float g_lds[128];
    __shared__ float be_lds[128];
    __shared__ unsigned short lists[13][128];
    __shared__ int cnt[13];

    const int t   = threadIdx.x;
    const int blk = blockIdx.x;
    const int b   = blk >> 5;
    const int n0  = (blk & 31) << 7;
    const float* ebase = embeds + ((size_t)b * 4096 + n0) * 128;

    for (int it = 0; it < 16; ++it) {
        int idx = it * 256 + t;
        int n = idx >> 5, c = idx & 31;
        float4 v = *(const float4*)(ebase + n * 128 + c * 4);
        *(float4*)(&e_lds[n][c * 4]) = v;
    }
    for (int i = t; i < 13 * 128; i += 256) b_lds[i] = bias[i];
    if (t < 128) { g_lds[t] = gamma[t]; be_lds[t] = beta[t]; }
    if (t < 13) cnt[t] = 0;
    __syncthreads();

    if (t < 128) {
        int ty = ntype[(size_t)b * 4096 + n0 + t];
        int slot = atomicAdd(&cnt[ty], 1);
        lists[ty][slot] = (unsigned short)t;
    }
    __syncthreads();

    const int lane = t & 63;
    const int wv   = t >> 6;

    for (int ty = 0; ty < 13; ++ty) {
        const int c = cnt[ty];
        __syncthreads();
        if (c > 0) {
            const float* Wt = W + (size_t)ty * 128 * 128;
            for (int it = 0; it < 16; ++it) {
                int idx = it * 256 + t;
                *(float4*)(&W_lds[idx >> 5][(idx & 31) * 4]) = *(const float4*)(Wt + idx * 4);
            }
        }
        __syncthreads();
        if (c == 0) continue;

        const int ngr = (c + 3) >> 2;
        for (int g = wv; g < ngr; g += 4) {
            int base = g * 4;
            int i1 = min(base + 1, c - 1), i2 = min(base + 2, c - 1), i3 = min(base + 3, c - 1);
            int nA = lists[ty][base], nB = lists[ty][i1], nC = lists[ty][i2], nD = lists[ty][i3];
            float a0 = 0, a1 = 0, a2 = 0, a3 = 0, a4 = 0, a5 = 0, a6 = 0, a7 = 0;
            for (int h = 0; h < 128; h += 4) {
                float4 eA = *(const float4*)(&e_lds[nA][h]);
                float4 eB = *(const float4*)(&e_lds[nB][h]);
                float4 eC = *(const float4*)(&e_lds[nC][h]);
                float4 eD = *(const float4*)(&e_lds[nD][h]);
                float w0 = W_lds[h + 0][lane],      w1 = W_lds[h + 1][lane];
                float w2 = W_lds[h + 2][lane],      w3 = W_lds[h + 3][lane];
                float v0 = W_lds[h + 0][lane + 64], v1 = W_lds[h + 1][lane + 64];
                float v2 = W_lds[h + 2][lane + 64], v3 = W_lds[h + 3][lane + 64];
                a0 += eA.x * w0 + eA.y * w1 + eA.z * w2 + eA.w * w3;
                a1 += eB.x * w0 + eB.y * w1 + eB.z * w2 + eB.w * w3;
                a2 += eC.x * w0 + eC.y * w1 + eC.z * w2 + eC.w * w3;
                a3 += eD.x * w0 + eD.y * w1 + eD.z * w2 + eD.w * w3;
                a4 += eA.x * v0 + eA.y * v1 + eA.z * v2 + eA.w * v3;
                a5 += eB.x * v0 + eB.y * v1 + eB.z * v2 + eB.w * v3;
                a6 += eC.x * v0 + eC.y * v1 + eC.z * v2 + eC.w * v3;
                a7 += eD.x * v0 + eD.y * v1 + eD.z * v2 + eD.w * v3;
            }
            float bl = b_lds[ty * 128 + lane], bh = b_lds[ty * 128 + lane + 64];
            a0 += bl; a1 += bl; a2 += bl; a3 += bl;
            a4 += bh; a5 += bh; a6 += bh; a7 += bh;
            int gbase = b * 4096 + n0;
            if (mask_on(mask8, gbase + nA)) { e_lds[nA][lane] = a0; e_lds[nA][lane + 64] = a4; }
            if (mask_on(mask8, gbase + nB)) { e_lds[nB][lane] = a1; e_lds[nB][lane + 64] = a5; }
            if (mask_on(mask8, gbase + nC)) { e_lds[nC][lane] = a2; e_lds[nC][lane + 64] = a6; }
            if (mask_on(mask8, gbase + nD)) { e_lds[nD][lane] = a3; e_lds[nD][lane + 64] = a7; }
        }
    }
    __syncthreads();

    for (int i = 0; i < 32; ++i) {
        int n = wv + i * 4;
        float2 v = *(const float2*)(&e_lds[n][lane * 2]);
        float s = v.x + v.y;
        float q = v.x * v.x + v.y * v.y;
        #pragma unroll
        for (int mskw = 32; mskw >= 1; mskw >>= 1) {
            s += __shfl_xor(s, mskw);
            q += __shfl_xor(q, mskw);
        }
        float mu  = s * 0.0078125f;
        float var = q * 0.0078125f - mu * mu;
        float r   = rsqrtf(var + 1e-5f);
        float2 o;
        o.x = (v.x - mu) * r * g_lds[lane * 2]     + be_lds[lane * 2];
        o.y = (v.y - mu) * r * g_lds[lane * 2 + 1] + be_lds[lane * 2 + 1];
        *(float2*)(&e_lds[n][lane * 2]) = o;
    }
    __syncthreads();

    const int nl = t & 127;
    const int hg = t >> 7;
    unsigned short* xrow = xT + (size_t)b * 128 * 4096 + n0 + nl;
    for (int i = 0; i < 64; ++i) {
        int h = hg * 64 + i;
        xrow[(size_t)h * 4096] = f2bf(e_lds[nl][h]);
    }
}

// swizzled LDS byte offset (rows padded to 80B = 40 bf16, 4x16B data blocks)
__device__ __forceinline__ int swz(int row, int blk16) {
    return row * 80 + (((blk16 ^ ((row >> 3) & 3)) & 3) << 4);
}

// ---------------------------------------------------------------------------
// Kernel 2: latT[b][h][m] = sum_n adj[b][n][m] * x[b][n][h]
// grid 512 = 8b x 64mt(32). 4 waves (2m x 2h), BK=32, 128 steps.
// Step = {LOAD(s+1) issue; COMPUTE(s); WRITE(s+1); barrier} — loads in
// flight across compute; barrier drain trivial (vmcnt consumed by WRITE).
// ---------------------------------------------------------------------------
__global__ __launch_bounds__(256) void k2_lat(
    const float* __restrict__ adj,
    const unsigned short* __restrict__ xT,
    unsigned short* __restrict__ latT)
{
    __shared__ unsigned short Al[2][32 * 40];   // [m][k] bf16, swizzled
    __shared__ unsigned short Bl[2][128 * 40];  // [h][k] bf16, swizzled

    const int t   = threadIdx.x;
    const int bid = blockIdx.x;
    const int b   = bid & 7;
    const int m0  = (bid >> 3) << 5;
    const float* adjb = adj + (size_t)b * 4096 * 2048;
    const unsigned short* xb = xT + (size_t)b * 128 * 4096;

    const int lane = t & 63, wv = t >> 6;
    const int wm = wv & 1, wh = wv >> 1;

    const int s_ml = (t & 7) << 2;      // A staging (t<128): 4 m's
    const int s_kp = t >> 3;            // A staging: k-pair 0..15
    const int s_h  = t >> 2;            // B staging: rows s_h, s_h+64
    const int s_u  = t & 3;             // B staging: 16B block in row

    const int g = lane >> 4;
    const int offA = swz(wm * 16 + (lane & 15), g);
    int offB[4];
    #pragma unroll
    for (int j = 0; j < 4; ++j)
        offB[j] = swz(wh * 64 + j * 16 + (lane & 15), g);

    float4 ar0, ar1;
    u32x4_t br0, br1;

    auto LOADT = [&](int k0) {
        if (t < 128) {
            const float* p = adjb + (size_t)(k0 + s_kp * 2) * 2048 + m0 + s_ml;
            ar0 = *(const float4*)(p);
            ar1 = *(const float4*)(p + 2048);
        }
        const unsigned short* q = xb + (size_t)s_h * 4096 + k0 + s_u * 8;
        br0 = *(const u32x4_t*)(q);
        br1 = *(const u32x4_t*)(q + (size_t)64 * 4096);
    };
    auto WRITET = [&](int buf) {
        if (t < 128) {
            const int blkk = s_kp >> 2, wrd = s_kp & 3;
            unsigned int p0 = cvtpk(ar0.x, ar1.x);
            unsigned int p1 = cvtpk(ar0.y, ar1.y);
            unsigned int p2 = cvtpk(ar0.z, ar1.z);
            unsigned int p3 = cvtpk(ar0.w, ar1.w);
            unsigned int pk[4] = { p0, p1, p2, p3 };
            #pragma unroll
            for (int j = 0; j < 4; ++j)
                *(unsigned int*)((char*)(&Al[buf][0]) + swz(s_ml + j, blkk) + wrd * 4) = pk[j];
        }
        *(u32x4_t*)((char*)(&Bl[buf][0]) + swz(s_h, s_u)) = br0;
        *(u32x4_t*)((char*)(&Bl[buf][0]) + swz(s_h + 64, s_u)) = br1;
    };

    f32x4_t acc[4];
    #pragma unroll
    for (int j = 0; j < 4; ++j) acc[j] = f32x4_t{0.f, 0.f, 0.f, 0.f};

    LOADT(0);
    WRITET(0);
    __syncthreads();

    for (int s = 0; s < 128; ++s) {
        const int buf = s & 1;
        if (s + 1 < 128) LOADT((s + 1) * 32);      // issue early
        bf16x8_t af = __builtin_bit_cast(bf16x8_t,
            *(const u32x4_t*)((const char*)(&Al[buf][0]) + offA));
        #pragma unroll
        for (int j = 0; j < 4; ++j) {
            bf16x8_t bfj = __builtin_bit_cast(bf16x8_t,
                *(const u32x4_t*)((const char*)(&Bl[buf][0]) + offB[j]));
            acc[j] = __builtin_amdgcn_mfma_f32_16x16x32_bf16(af, bfj, acc[j], 0, 0, 0);
        }
        if (s + 1 < 128) WRITET(buf ^ 1);          // write late (vmcnt here)
        __syncthreads();                           // drain trivial
    }

    const int mrow = m0 + wm * 16 + (lane >> 4) * 4;
    #pragma unroll
    for (int j = 0; j < 4; ++j) {
        int col = wh * 64 + j * 16 + (lane & 15);
        unsigned int o0 = cvtpk(acc[j][0], acc[j][1]);
        unsigned int o1 = cvtpk(acc[j][2], acc[j][3]);
        unsigned int* dst = (unsigned int*)(latT + (size_t)(b * 128 + col) * 2048 + mrow);
        dst[0] = o0; dst[1] = o1;
    }
}

// ---------------------------------------------------------------------------
// Kernel 3: ret[b][n][h] = sum_m adj[b][n][m] * latT[b][h][m]
// grid 1024 = 8b x 128nt(32). 4 waves (2n x 2h), BK=32, 64 steps.
// A rows k-contiguous (no transpose): load fp32x4 -> 2 cvt_pk -> b64 write.
// Same issue-early/write-late/end-barrier schedule as k2.
// ---------------------------------------------------------------------------
__global__ __launch_bounds__(256) void k3_ret(
    const float* __restrict__ adj,
    const unsigned short* __restrict__ latT,
    float* __restrict__ ret)
{
    __shared__ unsigned short Al[2][32 * 40];   // [n][k] bf16, swizzled
    __shared__ unsigned short Bl[2][128 * 40];  // [h][k] bf16, swizzled

    const int t   = threadIdx.x;
    const int bid = blockIdx.x;
    const int b   = bid & 7;
    const int n0  = (bid >> 3) << 5;
    const float* adjb = adj + (size_t)b * 4096 * 2048;
    const unsigned short* lb = latT + (size_t)b * 128 * 2048;

    const int lane = t & 63, wv = t >> 6;
    const int wn = wv & 1, wh = wv >> 1;

    const int s_r = t >> 3;          // A row 0..31
    const int s_c = (t & 7) * 4;     // A k-elem offset {0,4,...,28}
    const int s_h = t >> 2;          // B rows s_h, s_h+64
    const int s_u = t & 3;           // B 16B block in row

    const int g = lane >> 4;
    const int offA = swz(wn * 16 + (lane & 15), g);
    int offB[4];
    #pragma unroll
    for (int j = 0; j < 4; ++j)
        offB[j] = swz(wh * 64 + j * 16 + (lane & 15), g);

    f32x4_t ar;
    u32x4_t br0, br1;

    auto LOADT = [&](int k0) {
        ar = *(const f32x4_t*)(adjb + (size_t)(n0 + s_r) * 2048 + k0 + s_c);
        const unsigned short* q = lb + (size_t)s_h * 2048 + k0 + s_u * 8;
        br0 = *(const u32x4_t*)(q);
        br1 = *(const u32x4_t*)(q + (size_t)64 * 2048);
    };
    auto WRITET = [&](int buf) {
        u32x2_t p;
        p[0] = cvtpk(ar[0], ar[1]);
        p[1] = cvtpk(ar[2], ar[3]);
        *(u32x2_t*)((char*)(&Al[buf][0]) + swz(s_r, s_c >> 3) + ((s_c * 2) & 8)) = p;
        *(u32x4_t*)((char*)(&Bl[buf][0]) + swz(s_h, s_u)) = br0;
        *(u32x4_t*)((char*)(&Bl[buf][0]) + swz(s_h + 64, s_u)) = br1;
    };

    f32x4_t acc[4];
    #pragma unroll
    for (int j = 0; j < 4; ++j) acc[j] = f32x4_t{0.f, 0.f, 0.f, 0.f};

    LOADT(0);
    WRITET(0);
    __syncthreads();

    for (int s = 0; s < 64; ++s) {
        const int buf = s & 1;
        if (s + 1 < 64) LOADT((s + 1) * 32);
        bf16x8_t af = __builtin_bit_cast(bf16x8_t,
            *(const u32x4_t*)((const char*)(&Al[buf][0]) + offA));
        #pragma unroll
        for (int j = 0; j < 4; ++j) {
            bf16x8_t bfj = __builtin_bit_cast(bf16x8_t,
                *(const u32x4_t*)((const char*)(&Bl[buf][0]) + offB[j]));
            acc[j] = __builtin_amdgcn_mfma_f32_16x16x32_bf16(af, bfj, acc[j], 0, 0, 0);
        }
        if (s + 1 < 64) WRITET(buf ^ 1);
        __syncthreads();
    }

    const int nrow = n0 + wn * 16 + (lane >> 4) * 4;
    #pragma unroll
    for (int j = 0; j < 4; ++j) {
        int col = wh * 64 + j * 16 + (lane & 15);
        #pragma unroll
        for (int jj = 0; jj < 4; ++jj) {
            ret[((size_t)b * 4096 + nrow + jj) * 128 + col] = acc[j][jj];
        }
    }
}

// ---------------------------------------------------------------------------
extern "C" void kernel_launch(void* const* d_in, const int* in_sizes, int n_in,
                              void* d_out, int out_size, void* d_ws, size_t ws_size,
                              hipStream_t stream) {
    const float* adj    = (const float*)d_in[0];
    const float* embeds = (const float*)d_in[1];
    const int*   ntype  = (const int*)d_in[2];
    const unsigned char* mask8 = (const unsigned char*)d_in[3];
    const float* W      = (const float*)d_in[4];
    const float* bias   = (const float*)d_in[5];
    const float* gamma  = (const float*)d_in[6];
    const float* beta   = (const float*)d_in[7];
    float* ret = (float*)d_out;

    unsigned short* xT   = (unsigned short*)d_ws;                   // 8.39 MB
    unsigned short* latT = xT + (size_t)8 * 128 * 4096;             // 4.19 MB
    // ws needed: 12.6 MB

    hipLaunchKernelGGL(k1_typed_ln, dim3(256), dim3(256), 0, stream,
                       embeds, ntype, mask8, W, bias, gamma, beta, xT);
    hipLaunchKernelGGL(k2_lat, dim3(512), dim3(256), 0, stream, adj, xT, latT);
    hipLaunchKernelGGL(k3_ret, dim3(1024), dim3(256), 0, stream, adj, latT, ret);
}

// Round 5
// 215.397 us; speedup vs baseline: 2.1605x; 1.1600x over previous
//
#include <hip/hip_runtime.h>
#include <stdint.h>
#include <stddef.h>

// ---------------------------------------------------------------------------
// HHGNN: x = LN(route_by_type(embeds @ W[t] + b[t], mask)) ;
//        lat = adj^T @ x ; ret = adj @ lat
// Shapes: B=8, N=4096, M=2048, H=128, T=13. adj fp32 [B][N][M].
// R5 vs R4 (249.9us): rebuild GEMMs on the 2-phase template.
//  - BK=64 (2x MFMA per barrier, half the steps)
//  - B-panel staged via __builtin_amdgcn_global_load_lds (16B/lane), LDS
//    linear, bank-swizzle achieved by pre-swizzling the GLOBAL source
//    granule (m173 pattern): LDS row h granule g holds source granule
//    g^(h&7).
//  - A staged via regs + v_cvt_pk_bf16_f32 + granule-XOR ds_writes.
//  - All frag reads / A-writes verified <=2-way per 16-lane phase (the R2
//    profile showed 9.4M conflicts: the old 80B-pad swizzle was NOT clean).
// ws: xT 8.39MB + latT 4.19MB.
// ---------------------------------------------------------------------------

typedef float    f32x4_t  __attribute__((ext_vector_type(4)));
typedef __bf16   bf16x8_t __attribute__((ext_vector_type(8)));
typedef unsigned int u32x4_t __attribute__((ext_vector_type(4)));

__device__ __forceinline__ unsigned short f2bf(float f) {
    union { float f; unsigned int u; } v; v.f = f;
    unsigned int u = v.u;
    return (unsigned short)((u + 0x7FFFu + ((u >> 16) & 1u)) >> 16);
}

// packed RNE fp32x2 -> bf16x2 (lo=a, hi=b)
__device__ __forceinline__ unsigned int cvtpk(float a, float b) {
    unsigned int r;
    asm("v_cvt_pk_bf16_f32 %0, %1, %2" : "=v"(r) : "v"(a), "v"(b));
    return r;
}

__device__ __forceinline__ bool mask_on(const unsigned char* m, int gid) {
    return (m[gid] | m[(gid >> 2) << 2]) != 0;
}

// byte offset of 16B-granule g in row `row` of a [rows][64] bf16 LDS panel,
// granule-XOR swizzled by (row&7)
__device__ __forceinline__ int foff(int row, int g) {
    return row * 128 + (((g) ^ (row & 7)) << 4);
}

// ---------------------------------------------------------------------------
// B-panel staging: 128 rows x 64 bf16 via global_load_lds, 16B per lane.
// LDS dest linear (HW: wave-uniform base + lane*16); the bank swizzle is
// realized by fetching source granule (l&7)^(l>>3) per lane.
// ---------------------------------------------------------------------------
template<int GSTRIDE>
__device__ __forceinline__ void stage_B(const unsigned short* __restrict__ gb,
                                        int k0, unsigned short* ldsB, int t)
{
    const int l = t & 63, w = t >> 6;
    const int hsub = l >> 3;                       // row within 8-row group
    const int csrc = ((l & 7) ^ hsub) << 3;        // swizzled source k-granule
    #pragma unroll
    for (int i = 0; i < 4; ++i) {
        const int hbase = i * 32 + w * 8;
        const unsigned short* src = gb + (size_t)(hbase + hsub) * GSTRIDE + k0 + csrc;
        unsigned short* dst = ldsB + hbase * 64;   // wave-uniform base
        __builtin_amdgcn_global_load_lds(
            (__attribute__((address_space(1))) void*)src,
            (__attribute__((address_space(3))) void*)dst, 16, 0, 0);
    }
}

// ---------------------------------------------------------------------------
// Kernel 1: per-type linear + bias + mask + LayerNorm -> xT bf16 [B][H][N]
// (unchanged from R1)
// ---------------------------------------------------------------------------
__global__ __launch_bounds__(256) void k1_typed_ln(
    const float* __restrict__ embeds,
    const int*   __restrict__ ntype,
    const unsigned char* __restrict__ mask8,
    const float* __restrict__ W,
    const float* __restrict__ bias,
    const float* __restrict__ gamma,
    const float* __restrict__ beta,
    unsigned short* __restrict__ xT)
{
    __shared__ float e_lds[128][132];
    __shared__ float W_lds[128][128];
    __shared__ float b_lds[13 * 128];
    __shared__ float g_lds[128];
    __shared__ float be_lds[128];
    __shared__ unsigned short lists[13][128];
    __shared__ int cnt[13];

    const int t   = threadIdx.x;
    const int blk = blockIdx.x;
    const int b   = blk >> 5;
    const int n0  = (blk & 31) << 7;
    const float* ebase = embeds + ((size_t)b * 4096 + n0) * 128;

    for (int it = 0; it < 16; ++it) {
        int idx = it * 256 + t;
        int n = idx >> 5, c = idx & 31;
        float4 v = *(const float4*)(ebase + n * 128 + c * 4);
        *(float4*)(&e_lds[n][c * 4]) = v;
    }
    for (int i = t; i < 13 * 128; i += 256) b_lds[i] = bias[i];
    if (t < 128) { g_lds[t] = gamma[t]; be_lds[t] = beta[t]; }
    if (t < 13) cnt[t] = 0;
    __syncthreads();

    if (t < 128) {
        int ty = ntype[(size_t)b * 4096 + n0 + t];
        int slot = atomicAdd(&cnt[ty], 1);
        lists[ty][slot] = (unsigned short)t;
    }
    __syncthreads();

    const int lane = t & 63;
    const int wv   = t >> 6;

    for (int ty = 0; ty < 13; ++ty) {
        const int c = cnt[ty];
        __syncthreads();
        if (c > 0) {
            const float* Wt = W + (size_t)ty * 128 * 128;
            for (int it = 0; it < 16; ++it) {
                int idx = it * 256 + t;
                *(float4*)(&W_lds[idx >> 5][(idx & 31) * 4]) = *(const float4*)(Wt + idx * 4);
            }
        }
        __syncthreads();
        if (c == 0) continue;

        const int ngr = (c + 3) >> 2;
        for (int g = wv; g < ngr; g += 4) {
            int base = g * 4;
            int i1 = min(base + 1, c - 1), i2 = min(base + 2, c - 1), i3 = min(base + 3, c - 1);
            int nA = lists[ty][base], nB = lists[ty][i1], nC = lists[ty][i2], nD = lists[ty][i3];
            float a0 = 0, a1 = 0, a2 = 0, a3 = 0, a4 = 0, a5 = 0, a6 = 0, a7 = 0;
            for (int h = 0; h < 128; h += 4) {
                float4 eA = *(const float4*)(&e_lds[nA][h]);
                float4 eB = *(const float4*)(&e_lds[nB][h]);
                float4 eC = *(const float4*)(&e_lds[nC][h]);
                float4 eD = *(const float4*)(&e_lds[nD][h]);
                float w0 = W_lds[h + 0][lane],      w1 = W_lds[h + 1][lane];
                float w2 = W_lds[h + 2][lane],      w3 = W_lds[h + 3][lane];
                float v0 = W_lds[h + 0][lane + 64], v1 = W_lds[h + 1][lane + 64];
                float v2 = W_lds[h + 2][lane + 64], v3 = W_lds[h + 3][lane + 64];
                a0 += eA.x * w0 + eA.y * w1 + eA.z * w2 + eA.w * w3;
                a1 += eB.x * w0 + eB.y * w1 + eB.z * w2 + eB.w * w3;
                a2 += eC.x * w0 + eC.y * w1 + eC.z * w2 + eC.w * w3;
                a3 += eD.x * w0 + eD.y * w1 + eD.z * w2 + eD.w * w3;
                a4 += eA.x * v0 + eA.y * v1 + eA.z * v2 + eA.w * v3;
                a5 += eB.x * v0 + eB.y * v1 + eB.z * v2 + eB.w * v3;
                a6 += eC.x * v0 + eC.y * v1 + eC.z * v2 + eC.w * v3;
                a7 += eD.x * v0 + eD.y * v1 + eD.z * v2 + eD.w * v3;
            }
            float bl = b_lds[ty * 128 + lane], bh = b_lds[ty * 128 + lane + 64];
            a0 += bl; a1 += bl; a2 += bl; a3 += bl;
            a4 += bh; a5 += bh; a6 += bh; a7 += bh;
            int gbase = b * 4096 + n0;
            if (mask_on(mask8, gbase + nA)) { e_lds[nA][lane] = a0; e_lds[nA][lane + 64] = a4; }
            if (mask_on(mask8, gbase + nB)) { e_lds[nB][lane] = a1; e_lds[nB][lane + 64] = a5; }
            if (mask_on(mask8, gbase + nC)) { e_lds[nC][lane] = a2; e_lds[nC][lane + 64] = a6; }
            if (mask_on(mask8, gbase + nD)) { e_lds[nD][lane] = a3; e_lds[nD][lane + 64] = a7; }
        }
    }
    __syncthreads();

    for (int i = 0; i < 32; ++i) {
        int n = wv + i * 4;
        float2 v = *(const float2*)(&e_lds[n][lane * 2]);
        float s = v.x + v.y;
        float q = v.x * v.x + v.y * v.y;
        #pragma unroll
        for (int mskw = 32; mskw >= 1; mskw >>= 1) {
            s += __shfl_xor(s, mskw);
            q += __shfl_xor(q, mskw);
        }
        float mu  = s * 0.0078125f;
        float var = q * 0.0078125f - mu * mu;
        float r   = rsqrtf(var + 1e-5f);
        float2 o;
        o.x = (v.x - mu) * r * g_lds[lane * 2]     + be_lds[lane * 2];
        o.y = (v.y - mu) * r * g_lds[lane * 2 + 1] + be_lds[lane * 2 + 1];
        *(float2*)(&e_lds[n][lane * 2]) = o;
    }
    __syncthreads();

    const int nl = t & 127;
    const int hg = t >> 7;
    unsigned short* xrow = xT + (size_t)b * 128 * 4096 + n0 + nl;
    for (int i = 0; i < 64; ++i) {
        int h = hg * 64 + i;
        xrow[(size_t)h * 4096] = f2bf(e_lds[nl][h]);
    }
}

// ---------------------------------------------------------------------------
// Kernel 2: latT[b][h][m] = sum_n adj[b][n][m] * x[b][n][h]
// grid 512 = 8b x 64mt(32m). 4 waves (2m x 2h), BK=64, 64 steps.
// A: fp32 -> cvtpk -> granule-XOR ds_write (transpose). B: global_load_lds.
// Step: {issue A-loads(s+1) + stage_B(s+1); MFMA(s); cvt+write A(s+1); bar}
// ---------------------------------------------------------------------------
__global__ __launch_bounds__(256) void k2_lat(
    const float* __restrict__ adj,
    const unsigned short* __restrict__ xT,
    unsigned short* __restrict__ latT)
{
    __shared__ unsigned short Al[2][32 * 64];    // [m][k] bf16
    __shared__ unsigned short Bl[2][128 * 64];   // [h][k] bf16

    const int t   = threadIdx.x;
    const int bid = blockIdx.x;
    const int b   = bid & 7;
    const int m0  = (bid >> 3) << 5;
    const float* adjb = adj + (size_t)b * 4096 * 2048;
    const unsigned short* xb = xT + (size_t)b * 128 * 4096;

    const int lane = t & 63, wv = t >> 6;
    const int wm = wv & 1, wh = wv >> 1;

    const int a_kp = t >> 3;        // k-pair row 0..31 (k = 2*a_kp, 2*a_kp+1)
    const int a_m  = (t & 7) << 2;  // m chunk base

    const int fr = lane & 15, fg = lane >> 4;
    int offA[2], offB[4][2];
    #pragma unroll
    for (int kk = 0; kk < 2; ++kk) offA[kk] = foff(wm * 16 + fr, kk * 4 + fg);
    #pragma unroll
    for (int j = 0; j < 4; ++j)
        #pragma unroll
        for (int kk = 0; kk < 2; ++kk)
            offB[j][kk] = foff(wh * 64 + j * 16 + fr, kk * 4 + fg);

    f32x4_t ar0, ar1;
    auto LOAD_A = [&](int k0) {
        const float* p = adjb + (size_t)(k0 + a_kp * 2) * 2048 + m0 + a_m;
        ar0 = *(const f32x4_t*)(p);
        ar1 = *(const f32x4_t*)(p + 2048);
    };
    auto WRITE_A = [&](int buf) {
        const int g = a_kp >> 2, wrd = a_kp & 3;
        #pragma unroll
        for (int j = 0; j < 4; ++j) {
            const int m = a_m + j;
            unsigned int pk = cvtpk(ar0[j], ar1[j]);
            *(unsigned int*)((char*)(&Al[buf][0]) + m * 128 + ((g ^ (m & 7)) << 4) + wrd * 4) = pk;
        }
    };

    f32x4_t acc[4];
    #pragma unroll
    for (int j = 0; j < 4; ++j) acc[j] = f32x4_t{0.f, 0.f, 0.f, 0.f};

    LOAD_A(0);
    stage_B<4096>(xb, 0, &Bl[0][0], t);
    WRITE_A(0);
    __syncthreads();

    for (int s = 0; s < 64; ++s) {
        const int buf = s & 1;
        if (s < 63) {
            LOAD_A((s + 1) * 64);
            stage_B<4096>(xb, (s + 1) * 64, &Bl[buf ^ 1][0], t);
        }
        bf16x8_t af[2];
        #pragma unroll
        for (int kk = 0; kk < 2; ++kk)
            af[kk] = __builtin_bit_cast(bf16x8_t,
                *(const u32x4_t*)((const char*)(&Al[buf][0]) + offA[kk]));
        #pragma unroll
        for (int j = 0; j < 4; ++j) {
            #pragma unroll
            for (int kk = 0; kk < 2; ++kk) {
                bf16x8_t bfj = __builtin_bit_cast(bf16x8_t,
                    *(const u32x4_t*)((const char*)(&Bl[buf][0]) + offB[j][kk]));
                acc[j] = __builtin_amdgcn_mfma_f32_16x16x32_bf16(af[kk], bfj, acc[j], 0, 0, 0);
            }
        }
        if (s < 63) WRITE_A(buf ^ 1);
        __syncthreads();
    }

    const int mrow = m0 + wm * 16 + (lane >> 4) * 4;
    #pragma unroll
    for (int j = 0; j < 4; ++j) {
        int col = wh * 64 + j * 16 + fr;
        unsigned int o0 = cvtpk(acc[j][0], acc[j][1]);
        unsigned int o1 = cvtpk(acc[j][2], acc[j][3]);
        unsigned int* dst = (unsigned int*)(latT + (size_t)(b * 128 + col) * 2048 + mrow);
        dst[0] = o0; dst[1] = o1;
    }
}

// ---------------------------------------------------------------------------
// Kernel 3: ret[b][n][h] = sum_m adj[b][n][m] * latT[b][h][m]
// grid 1024 = 8b x 128nt(32n). 4 waves (2n x 2h), BK=64, 32 steps.
// A: fp32 k-contiguous -> 4 cvtpk -> one b128 granule-XOR write (no scatter).
// B: global_load_lds, same pre-swizzle.
// ---------------------------------------------------------------------------
__global__ __launch_bounds__(256) void k3_ret(
    const float* __restrict__ adj,
    const unsigned short* __restrict__ latT,
    float* __restrict__ ret)
{
    __shared__ unsigned short Al[2][32 * 64];    // [n][k] bf16
    __shared__ unsigned short Bl[2][128 * 64];   // [h][k] bf16

    const int t   = threadIdx.x;
    const int bid = blockIdx.x;
    const int b   = bid & 7;
    const int n0  = (bid >> 3) << 5;
    const float* adjb = adj + (size_t)b * 4096 * 2048;
    const unsigned short* lb = latT + (size_t)b * 128 * 2048;

    const int lane = t & 63, wv = t >> 6;
    const int wn = wv & 1, wh = wv >> 1;

    const int a_r = t >> 3;         // n-row 0..31
    const int a_c = t & 7;          // k-granule 0..7

    const int fr = lane & 15, fg = lane >> 4;
    int offA[2], offB[4][2];
    #pragma unroll
    for (int kk = 0; kk < 2; ++kk) offA[kk] = foff(wn * 16 + fr, kk * 4 + fg);
    #pragma unroll
    for (int j = 0; j < 4; ++j)
        #pragma unroll
        for (int kk = 0; kk < 2; ++kk)
            offB[j][kk] = foff(wh * 64 + j * 16 + fr, kk * 4 + fg);

    f32x4_t ar0, ar1;
    auto LOAD_A = [&](int k0) {
        const float* p = adjb + (size_t)(n0 + a_r) * 2048 + k0 + a_c * 8;
        ar0 = *(const f32x4_t*)(p);
        ar1 = *(const f32x4_t*)(p + 4);
    };
    auto WRITE_A = [&](int buf) {
        u32x4_t pk;
        pk[0] = cvtpk(ar0[0], ar0[1]);
        pk[1] = cvtpk(ar0[2], ar0[3]);
        pk[2] = cvtpk(ar1[0], ar1[1]);
        pk[3] = cvtpk(ar1[2], ar1[3]);
        *(u32x4_t*)((char*)(&Al[buf][0]) + a_r * 128 + ((a_c ^ (a_r & 7)) << 4)) = pk;
    };

    f32x4_t acc[4];
    #pragma unroll
    for (int j = 0; j < 4; ++j) acc[j] = f32x4_t{0.f, 0.f, 0.f, 0.f};

    LOAD_A(0);
    stage_B<2048>(lb, 0, &Bl[0][0], t);
    WRITE_A(0);
    __syncthreads();

    for (int s = 0; s < 32; ++s) {
        const int buf = s & 1;
        if (s < 31) {
            LOAD_A((s + 1) * 64);
            stage_B<2048>(lb, (s + 1) * 64, &Bl[buf ^ 1][0], t);
        }
        bf16x8_t af[2];
        #pragma unroll
        for (int kk = 0; kk < 2; ++kk)
            af[kk] = __builtin_bit_cast(bf16x8_t,
                *(const u32x4_t*)((const char*)(&Al[buf][0]) + offA[kk]));
        #pragma unroll
        for (int j = 0; j < 4; ++j) {
            #pragma unroll
            for (int kk = 0; kk < 2; ++kk) {
                bf16x8_t bfj = __builtin_bit_cast(bf16x8_t,
                    *(const u32x4_t*)((const char*)(&Bl[buf][0]) + offB[j][kk]));
                acc[j] = __builtin_amdgcn_mfma_f32_16x16x32_bf16(af[kk], bfj, acc[j], 0, 0, 0);
            }
        }
        if (s < 31) WRITE_A(buf ^ 1);
        __syncthreads();
    }

    const int nrow = n0 + wn * 16 + (lane >> 4) * 4;
    #pragma unroll
    for (int j = 0; j < 4; ++j) {
        int col = wh * 64 + j * 16 + fr;
        #pragma unroll
        for (int jj = 0; jj < 4; ++jj) {
            ret[((size_t)b * 4096 + nrow + jj) * 128 + col] = acc[j][jj];
        }
    }
}

// ---------------------------------------------------------------------------
extern "C" void kernel_launch(void* const* d_in, const int* in_sizes, int n_in,
                              void* d_out, int out_size, void* d_ws, size_t ws_size,
                              hipStream_t stream) {
    const float* adj    = (const float*)d_in[0];
    const float* embeds = (const float*)d_in[1];
    const int*   ntype  = (const int*)d_in[2];
    const unsigned char* mask8 = (const unsigned char*)d_in[3];
    const float* W      = (const float*)d_in[4];
    const float* bias   = (const float*)d_in[5];
    const float* gamma  = (const float*)d_in[6];
    const float* beta   = (const float*)d_in[7];
    float* ret = (float*)d_out;

    unsigned short* xT   = (unsigned short*)d_ws;                   // 8.39 MB
    unsigned short* latT = xT + (size_t)8 * 128 * 4096;             // 4.19 MB
    // ws needed: 12.6 MB

    hipLaunchKernelGGL(k1_typed_ln, dim3(256), dim3(256), 0, stream,
                       embeds, ntype, mask8, W, bias, gamma, beta, xT);
    hipLaunchKernelGGL(k2_lat, dim3(512), dim3(256), 0, stream, adj, xT, latT);
    hipLaunchKernelGGL(k3_ret, dim3(1024), dim3(256), 0, stream, adj, latT, ret);
}